// Round 1
// baseline (268.540 us; speedup 1.0000x reference)
//
#include <hip/hip_runtime.h>
#include <math.h>

#define H_N 1024
#define M_N 8
#define HM 8192

static __device__ __forceinline__ float log_eps(float x) {
    const float EPS_TINY = 1.17549435e-38f;
    return __logf(x <= 0.0f ? EPS_TINY : x);
}

// ---------------- kernel 1: st_acc[j] += sum_i w[i][j] * o[i] (split-K partials) ----
__global__ __launch_bounds__(256) void gemv_partial(const float* __restrict__ w,
                                                    const float* __restrict__ o,
                                                    float* __restrict__ st_acc) {
    const int jb = blockIdx.x & 7;   // 8 j-blocks of 1024 columns
    const int ic = blockIdx.x >> 3;  // 64 i-chunks of 128 rows
    const int j0 = jb * 1024 + threadIdx.x * 4;
    const int i0 = ic * 128;
    float ax = 0.f, ay = 0.f, az = 0.f, aw = 0.f;
    const float* wp = w + (size_t)i0 * HM + j0;
#pragma unroll 4
    for (int i = 0; i < 128; ++i) {
        const float ov = o[i0 + i];
        const float4 wv = *reinterpret_cast<const float4*>(wp);
        ax += wv.x * ov; ay += wv.y * ov; az += wv.z * ov; aw += wv.w * ov;
        wp += HM;
    }
    atomicAdd(&st_acc[j0 + 0], ax);
    atomicAdd(&st_acc[j0 + 1], ay);
    atomicAdd(&st_acc[j0 + 2], az);
    atomicAdd(&st_acc[j0 + 3], aw);
}

// ---------------- kernel 2: per-row state update + softmax + small outputs ---------
__global__ __launch_bounds__(256) void row_kernel(
    const float* __restrict__ x, const float* __restrict__ s,
    const float* __restrict__ a, const float* __restrict__ zi,
    const float* __restrict__ zj, const float* __restrict__ p,
    const float* __restrict__ pi, const float* __restrict__ pj,
    const float* __restrict__ b, const float* __restrict__ noise,
    const float* __restrict__ ga, const float* __restrict__ gw,
    const float* __restrict__ gb, const float* __restrict__ gs,
    const float* __restrict__ k, const float* __restrict__ st_acc,
    float* __restrict__ out) {
    const int r = blockIdx.x * blockDim.x + threadIdx.x;
    if (r >= H_N) return;

    const float gwv = gw[0], gav = ga[0], gbv = gb[0], gsv = gs[0], kv = k[0], pv = p[0];
    const float c = kv * 0.001f / 10.0f;   // k*DT/TP

    float* o_new  = out;
    float* s_new  = out + (size_t)HM;
    float* a_new  = out + (size_t)2 * HM;
    float* zi_new = out + (size_t)3 * HM;
    float* zj_new = out + (size_t)4 * HM;
    float* p_new  = out + (size_t)5 * HM;          // 1 element
    float* pi_new = out + (size_t)5 * HM + 1;
    float* pj_new = out + (size_t)6 * HM + 1;
    float* b_new  = out + (size_t)7 * HM + 1 + (size_t)2 * HM * HM;

    const int base = r * M_N;
    float sv[M_N], ev[M_N];
    float mx = -3.0e38f;
#pragma unroll
    for (int m = 0; m < M_N; ++m) {
        const int i = base + m;
        const float st = gwv * (b[i] + st_acc[i]);
        const float sn = s[i] + 0.02f * (st - a[i] + log_eps(x[i]) + gsv * noise[i] - s[i]);
        sv[m] = sn;
        mx = fmaxf(mx, sn);
    }
    float sum = 0.f;
#pragma unroll
    for (int m = 0; m < M_N; ++m) { ev[m] = __expf(sv[m] - mx); sum += ev[m]; }
    const float rs = 1.0f / sum;
#pragma unroll
    for (int m = 0; m < M_N; ++m) {
        const int i = base + m;
        const float on  = ev[m] * rs;
        const float an  = a[i]  + (float)(0.001 / 2.7)  * (gav * on - a[i]);
        const float zin = zi[i] + (float)(0.001 / 0.24) * (on - zi[i]);
        const float zjn = zj[i] + (float)(0.001 / 0.24) * (on - zj[i]);
        const float pin = pi[i] + c * (zin - pi[i]);
        const float pjn = pj[i] + c * (zjn - pj[i]);
        o_new[i]  = on;
        s_new[i]  = sv[m];
        a_new[i]  = an;
        zi_new[i] = zin;
        zj_new[i] = zjn;
        pi_new[i] = pin;
        pj_new[i] = pjn;
        b_new[i]  = gbv * log_eps(pjn);
    }
    if (r == 0) p_new[0] = pv + c * (1.0f - pv);
}

// ---------------- kernel 3: pij_new + w_new (dominant, ~768 MB traffic) ------------
__global__ __launch_bounds__(256) void outer_kernel(
    const float* __restrict__ pij, const float* __restrict__ out_ro,
    float* __restrict__ out, const float* __restrict__ p,
    const float* __restrict__ k) {
    const float* zi_new = out_ro + (size_t)3 * HM;
    const float* zj_new = out_ro + (size_t)4 * HM;
    const float* pi_new = out_ro + (size_t)5 * HM + 1;
    const float* pj_new = out_ro + (size_t)6 * HM + 1;
    float* pij_new = out + (size_t)7 * HM + 1;
    float* w_new   = pij_new + (size_t)HM * HM;

    const float kv = k[0], pv = p[0];
    const float c  = kv * 0.001f / 10.0f;
    const float pn = pv + c * (1.0f - pv);

    const size_t nvec   = (size_t)HM * HM / 4;
    const size_t stride = (size_t)gridDim.x * blockDim.x;
    for (size_t v = (size_t)blockIdx.x * blockDim.x + threadIdx.x; v < nvec; v += stride) {
        const size_t idx = v * 4;
        const int I = (int)(idx >> 13);
        const int J = (int)(idx & 8191);
        const float ziI = zi_new[I];
        const float piI = pi_new[I];
        const float4 pv4 = *reinterpret_cast<const float4*>(&pij[idx]);
        const float zj0 = zj_new[J + 0], zj1 = zj_new[J + 1], zj2 = zj_new[J + 2], zj3 = zj_new[J + 3];
        const float pj0 = pj_new[J + 0], pj1 = pj_new[J + 1], pj2 = pj_new[J + 2], pj3 = pj_new[J + 3];

        const float q0 = pv4.x + c * (ziI * zj0 - pv4.x);
        const float q1 = pv4.y + c * (ziI * zj1 - pv4.y);
        const float q2 = pv4.z + c * (ziI * zj2 - pv4.z);
        const float q3 = pv4.w + c * (ziI * zj3 - pv4.w);

        pij_new[idx + 0] = q0;
        pij_new[idx + 1] = q1;
        pij_new[idx + 2] = q2;
        pij_new[idx + 3] = q3;

        const float v0 = __fdividef(pn * q0, piI * pj0);
        const float v1 = __fdividef(pn * q1, piI * pj1);
        const float v2 = __fdividef(pn * q2, piI * pj2);
        const float v3 = __fdividef(pn * q3, piI * pj3);

        w_new[idx + 0] = log_eps(v0);
        w_new[idx + 1] = log_eps(v1);
        w_new[idx + 2] = log_eps(v2);
        w_new[idx + 3] = log_eps(v3);
    }
}

extern "C" void kernel_launch(void* const* d_in, const int* in_sizes, int n_in,
                              void* d_out, int out_size, void* d_ws, size_t ws_size,
                              hipStream_t stream) {
    const float* x     = (const float*)d_in[0];
    const float* s     = (const float*)d_in[1];
    const float* o     = (const float*)d_in[2];
    const float* a     = (const float*)d_in[3];
    const float* zi    = (const float*)d_in[4];
    const float* zj    = (const float*)d_in[5];
    const float* p     = (const float*)d_in[6];
    const float* pi    = (const float*)d_in[7];
    const float* pj    = (const float*)d_in[8];
    const float* pij   = (const float*)d_in[9];
    const float* b     = (const float*)d_in[10];
    const float* w     = (const float*)d_in[11];
    const float* noise = (const float*)d_in[12];
    const float* ga    = (const float*)d_in[13];
    const float* gw    = (const float*)d_in[14];
    const float* gb    = (const float*)d_in[15];
    const float* gs    = (const float*)d_in[16];
    const float* k     = (const float*)d_in[17];

    float* out = (float*)d_out;
    float* st_acc = (float*)d_ws;

    hipMemsetAsync(st_acc, 0, HM * sizeof(float), stream);
    gemv_partial<<<512, 256, 0, stream>>>(w, o, st_acc);
    row_kernel<<<(H_N + 255) / 256, 256, 0, stream>>>(
        x, s, a, zi, zj, p, pi, pj, b, noise, ga, gw, gb, gs, k, st_acc, out);
    outer_kernel<<<2048, 256, 0, stream>>>(pij, out, out, p, k);
}